// Round 10
// baseline (128.871 us; speedup 1.0000x reference)
//
#include <hip/hip_runtime.h>
#include <stdint.h>

// DiffAttention: O[n,h,d] = sum_l sigmoid(q_n.k_l) v_l / sum_l sigmoid(q_n.k_l)
// N=L=4096, H=8, M=D=64, fp32 in/out, bf16 MFMA compute.
//
// R10 = R9 (pi-permuted V kills the P lane-exchange; LDS dbuf, 1 barrier/tile)
// + two cuts:
//  (a) paired-rcp sigmoid: r=rcp((1+A)(1+B)); sa=r*(1+B); sb=r*(1+A).
//      3 trans + 5 VALU per pair vs 4 trans + 2 VALU. Trans pipe (16cyc/wave64
//      op) is the measured floor (27.5us busy = 51% of 54us) -> -4.3us.
//      Pairs are overflow-safe (t<=63.5 -> product <= 2^127); quads are not.
//  (b) Onum in bf16: halves epilogue WRITE and combine reads.
// Standing lessons: R3 never force 8 waves/EU (spill); R5 no __threadfence
// split-K (L2 storm); R6 residency register-capped ~4 blocks/CU; R8 direct
// global loads thrash L1 (107us); 2^22 LDS "conflicts" = b128 phase overhead.

typedef __bf16 bf16x8 __attribute__((ext_vector_type(8)));
typedef __bf16 bf16x2 __attribute__((ext_vector_type(2)));
typedef float  f32x2  __attribute__((ext_vector_type(2)));
typedef float  f32x16 __attribute__((ext_vector_type(16)));
typedef unsigned u32x4 __attribute__((ext_vector_type(4)));

constexpr int NH = 8, MD = 64, NL = 4096, NN = 4096;
constexpr size_t ONUM_ELEMS = (size_t)NN * NH * MD;  // per split (bf16)
constexpr size_t Z_ELEMS    = (size_t)NN * NH;       // per split (f32)
constexpr size_t KB_ELEMS   = (size_t)NH * NL * MD;  // bf16
constexpr size_t VTB_ELEMS  = (size_t)NH * NL * MD;  // bf16

__device__ __forceinline__ unsigned packbf2(float a, float b) {
  bf16x2 t = __builtin_convertvector((f32x2){a, b}, bf16x2);
  return __builtin_bit_cast(unsigned, t);
}

__device__ __forceinline__ void glds16(const void* g, void* l) {
  __builtin_amdgcn_global_load_lds(
      (const __attribute__((address_space(1))) unsigned int*)g,
      (__attribute__((address_space(3))) unsigned int*)l, 16, 0, 0);
}

// ---------------- prepass: one block per (h, l-tile) ----------------
__global__ __launch_bounds__(256) void diffattn_prepass(
    const float* __restrict__ Kg, const float* __restrict__ Vg,
    unsigned short* __restrict__ Kb, unsigned short* __restrict__ Vtb) {
  __shared__ __attribute__((aligned(16))) unsigned short Vt_lds[64 * 64];
  const int tid = threadIdx.x;
  const int h = blockIdx.x & 7;
  const int t = blockIdx.x >> 3;

  // ---- K: [l][h][m] fp32 -> [h][l][m] bf16, 16B chunks swizzled by l&7
#pragma unroll
  for (int e = 0; e < 2; ++e) {
    const int g = tid * 2 + e;
    const int l = g >> 3, c = g & 7;
    const float* kp = Kg + (((size_t)(t * 64 + l) * NH + h) * MD) + c * 8;
    const float4 a = *(const float4*)kp;
    const float4 b = *(const float4*)(kp + 4);
    unsigned out[4] = {packbf2(a.x, a.y), packbf2(a.z, a.w),
                       packbf2(b.x, b.y), packbf2(b.z, b.w)};
    unsigned short* dst =
        Kb + ((size_t)h * NL + t * 64 + l) * MD + ((c ^ (l & 7)) * 8);
    *(uint4*)dst = *(const uint4*)out;
  }

  // ---- V: [l][h][d] fp32 -> LDS transpose (l bit2<->bit3 swapped: the
  //      pi-permutation that makes PV's A-frag equal QK's D regs) ->
  //      [h][t][d][p] bf16, 16B chunks swizzled by d&7
  {
    const int lr = tid & 63, dbase = (tid >> 6) * 16;
    const int pl = (lr & 0x33) | ((lr & 4) << 1) | ((lr & 8) >> 1);
    const float* vp = Vg + (((size_t)(t * 64 + lr) * NH + h) * MD) + dbase;
#pragma unroll
    for (int i = 0; i < 4; ++i) {
      const float4 v = *(const float4*)(vp + i * 4);
      const int d0 = dbase + i * 4;
      Vt_lds[(d0 + 0) * 64 + pl] = __builtin_bit_cast(unsigned short, (__bf16)v.x);
      Vt_lds[(d0 + 1) * 64 + pl] = __builtin_bit_cast(unsigned short, (__bf16)v.y);
      Vt_lds[(d0 + 2) * 64 + pl] = __builtin_bit_cast(unsigned short, (__bf16)v.z);
      Vt_lds[(d0 + 3) * 64 + pl] = __builtin_bit_cast(unsigned short, (__bf16)v.w);
    }
  }
  __syncthreads();
#pragma unroll
  for (int e = 0; e < 2; ++e) {
    const int g = tid * 2 + e;
    const int d = g >> 3, cl = g & 7;
    const uint4 chunk = *(const uint4*)&Vt_lds[d * 64 + cl * 8];
    unsigned short* dst = Vtb + ((size_t)(h * 64 + t) * 64 + d) * 64 +
                          ((cl ^ (d & 7)) * 8);
    *(uint4*)dst = chunk;
  }
}

// ---------------- partial ----------------
__global__ __launch_bounds__(256, 4) void diffattn_partial(
    const float* __restrict__ Qg, const unsigned short* __restrict__ Kb,
    const unsigned short* __restrict__ Vtb, unsigned short* __restrict__ Onum,
    float* __restrict__ Zp, int nsplit, int lLen) {
  __shared__ __attribute__((aligned(16))) unsigned short Ksh[2][64 * 64];
  __shared__ __attribute__((aligned(16))) unsigned short Vtsh[2][64 * 64];

  const int tid  = threadIdx.x;
  const int w    = tid >> 6;
  const int lane = tid & 63;
  const int col  = lane & 31;
  const int hi   = lane >> 5;

  const int h     = blockIdx.x & 7;
  const int tmp   = blockIdx.x >> 3;
  const int split = tmp % nsplit;
  const int n0    = (tmp / nsplit) * 128;
  const int lBeg  = split * lLen;

  // Q fragments (B operand), prescaled by -log2e: sigma = rcp(1+exp2(d1)).
  bf16x8 qf[4];
  {
    const float* qp = Qg + ((size_t)(n0 + w * 32 + col) * NH + h) * MD;
    const float c = -1.4426950408889634f;
#pragma unroll
    for (int kc = 0; kc < 4; ++kc) {
      const float4 x = *(const float4*)(qp + kc * 16 + hi * 8);
      const float4 y = *(const float4*)(qp + kc * 16 + hi * 8 + 4);
      bf16x8 f;
      f[0] = (__bf16)(c * x.x); f[1] = (__bf16)(c * x.y);
      f[2] = (__bf16)(c * x.z); f[3] = (__bf16)(c * x.w);
      f[4] = (__bf16)(c * y.x); f[5] = (__bf16)(c * y.y);
      f[6] = (__bf16)(c * y.z); f[7] = (__bf16)(c * y.w);
      qf[kc] = f;
    }
  }

  f32x16 oacc[2];
#pragma unroll
  for (int i = 0; i < 16; ++i) { oacc[0][i] = 0.f; oacc[1][i] = 0.f; }
  float zacc = 0.f;
  const f32x16 zf = {};

  const char* kgh = (const char*)(Kb + (size_t)h * NL * MD);
  const char* vgh = (const char*)(Vtb + (size_t)h * NL * MD);
  const int o = w * 2048 + lane * 16;
  const int T = lLen >> 6;

  // prefetch tile 0 into buffer 0
  {
    const char* kgb = kgh + (size_t)lBeg * 128;
    const char* vgb = vgh + (size_t)lBeg * 128;
    glds16(kgb + o,        (char*)Ksh[0]  + w * 2048);
    glds16(kgb + o + 1024, (char*)Ksh[0]  + w * 2048 + 1024);
    glds16(vgb + o,        (char*)Vtsh[0] + w * 2048);
    glds16(vgb + o + 1024, (char*)Vtsh[0] + w * 2048 + 1024);
  }

  for (int t = 0; t < T; ++t) {
    const int cur = t & 1;
    __syncthreads();  // 1 barrier/tile; drains ~1-tile-old glds loads (cheap)
    if (t + 1 < T) {
      const char* kgb = kgh + (size_t)(lBeg + (t + 1) * 64) * 128;
      const char* vgb = vgh + (size_t)(lBeg + (t + 1) * 64) * 128;
      glds16(kgb + o,        (char*)Ksh[cur ^ 1]  + w * 2048);
      glds16(kgb + o + 1024, (char*)Ksh[cur ^ 1]  + w * 2048 + 1024);
      glds16(vgb + o,        (char*)Vtsh[cur ^ 1] + w * 2048);
      glds16(vgb + o + 1024, (char*)Vtsh[cur ^ 1] + w * 2048 + 1024);
    }

    // ---- QK: D1[lh] (32 l x 32 q) = K(32l x 64k) x Qscaled(64k x 32q)
    f32x16 d1[2];
#pragma unroll
    for (int lh = 0; lh < 2; ++lh) {
      const int rowK = lh * 32 + col;
      const char* kp = (const char*)Ksh[cur] + rowK * 128;
      const int swk = rowK & 7;
      {
        const bf16x8 kf = *(const bf16x8*)(kp + ((hi ^ swk) * 16));
        d1[lh] = __builtin_amdgcn_mfma_f32_32x32x16_bf16(kf, qf[0], zf, 0, 0, 0);
      }
#pragma unroll
      for (int kc = 1; kc < 4; ++kc) {
        const bf16x8 kf = *(const bf16x8*)(kp + (((kc << 1) | hi) ^ swk) * 16);
        d1[lh] = __builtin_amdgcn_mfma_f32_32x32x16_bf16(kf, qf[kc], d1[lh], 0, 0, 0);
      }
    }

    // ---- V frag batch A — in flight under the sigmoid burst
    const char* vb = (const char*)Vtsh[cur];
    bf16x8 vfA[2][2];
#pragma unroll
    for (int c = 0; c < 2; ++c)
#pragma unroll
      for (int ds = 0; ds < 2; ++ds) {
        const int rowV = ds * 32 + col;
        vfA[c][ds] = *(const bf16x8*)(vb + rowV * 128 +
                                      (((c << 1) | hi) ^ (rowV & 7)) * 16);
      }

    // ---- paired-rcp sigmoid + Z + pack (pairs are consecutive pi-l)
    unsigned pk[2][8];
#pragma unroll
    for (int lh = 0; lh < 2; ++lh) {
#pragma unroll
      for (int p = 0; p < 8; ++p) {
        const float eA = __builtin_amdgcn_exp2f(d1[lh][2 * p]);
        const float eB = __builtin_amdgcn_exp2f(d1[lh][2 * p + 1]);
        const float tA = 1.0f + eA;
        const float tB = 1.0f + eB;
        const float r  = __builtin_amdgcn_rcpf(tA * tB);
        const float sa = r * tB;
        const float sb = r * tA;
        zacc += sa + sb;
        pk[lh][p] = packbf2(sa, sb);
      }
    }

    // ---- PV: O += P x V(pi-ordered). A-frag = pk[lh] dwords, no exchange.
#pragma unroll
    for (int c = 0; c < 2; ++c) {
      const bf16x8 pf = __builtin_bit_cast(bf16x8, *(const u32x4*)&pk[0][c * 4]);
#pragma unroll
      for (int ds = 0; ds < 2; ++ds)
        oacc[ds] = __builtin_amdgcn_mfma_f32_32x32x16_bf16(pf, vfA[c][ds],
                                                           oacc[ds], 0, 0, 0);
    }
#pragma unroll
    for (int c = 0; c < 2; ++c)
#pragma unroll
      for (int ds = 0; ds < 2; ++ds) {
        const int rowV = ds * 32 + col;
        vfA[c][ds] = *(const bf16x8*)(vb + rowV * 128 +
                                      ((((c + 2) << 1 | hi)) ^ (rowV & 7)) * 16);
      }
#pragma unroll
    for (int c = 0; c < 2; ++c) {
      const bf16x8 pf = __builtin_bit_cast(bf16x8, *(const u32x4*)&pk[1][c * 4]);
#pragma unroll
      for (int ds = 0; ds < 2; ++ds)
        oacc[ds] = __builtin_amdgcn_mfma_f32_32x32x16_bf16(pf, vfA[c][ds],
                                                           oacc[ds], 0, 0, 0);
    }
  }

  // ---- epilogue: store bf16 numerator + f32 Z partial
  const float zrow = zacc + __shfl_xor(zacc, 32, 64);
  if (hi == 0)
    Zp[(size_t)split * Z_ELEMS + (size_t)(n0 + w * 32 + col) * NH + h] = zrow;

  unsigned short* onum = Onum + (size_t)split * ONUM_ELEMS;
#pragma unroll
  for (int ds = 0; ds < 2; ++ds) {
    const int d = ds * 32 + col;
#pragma unroll
    for (int r = 0; r < 16; ++r) {
      const int row = (r & 3) + 8 * (r >> 2) + 4 * hi;
      onum[((size_t)(n0 + w * 32 + row) * NH + h) * MD + d] =
          __builtin_bit_cast(unsigned short, (__bf16)oacc[ds][r]);
    }
  }
}

// ---------------- combine: one 8-elem bf16 chunk per thread ----------------
__global__ __launch_bounds__(256) void diffattn_combine(
    const unsigned short* __restrict__ Onum, const float* __restrict__ Zp,
    float* __restrict__ Og, int nsplit) {
  const int idx = blockIdx.x * 256 + threadIdx.x;
  if (idx >= (int)(ONUM_ELEMS / 8)) return;
  const int nh = idx >> 3;          // (n*NH+h)
  const int c8 = (idx & 7) * 8;     // d offset
  float z = 0.f;
  float acc[8] = {0.f, 0.f, 0.f, 0.f, 0.f, 0.f, 0.f, 0.f};
  for (int s = 0; s < nsplit; ++s) {
    z += Zp[(size_t)s * Z_ELEMS + nh];
    const uint4 t = *(const uint4*)(Onum + (size_t)s * ONUM_ELEMS +
                                    (size_t)nh * MD + c8);
    const unsigned u[4] = {t.x, t.y, t.z, t.w};
#pragma unroll
    for (int j = 0; j < 4; ++j) {
      acc[2 * j]     += __builtin_bit_cast(float, u[j] << 16);
      acc[2 * j + 1] += __builtin_bit_cast(float, u[j] & 0xffff0000u);
    }
  }
  const float zi = __builtin_amdgcn_rcpf(z);
  float4 r0 = make_float4(acc[0] * zi, acc[1] * zi, acc[2] * zi, acc[3] * zi);
  float4 r1 = make_float4(acc[4] * zi, acc[5] * zi, acc[6] * zi, acc[7] * zi);
  float* out = Og + (size_t)nh * MD + c8;
  *(float4*)out = r0;
  *(float4*)(out + 4) = r1;
}

extern "C" void kernel_launch(void* const* d_in, const int* in_sizes, int n_in,
                              void* d_out, int out_size, void* d_ws, size_t ws_size,
                              hipStream_t stream) {
  const float* Q = (const float*)d_in[0];
  const float* K = (const float*)d_in[1];
  const float* V = (const float*)d_in[2];
  float* O = (float*)d_out;

  const size_t conv_bytes = (KB_ELEMS + VTB_ELEMS) * sizeof(unsigned short);
  int nsplit = 4;
  while (nsplit > 1 &&
         (size_t)nsplit * (ONUM_ELEMS * 2 + Z_ELEMS * 4) + conv_bytes > ws_size)
    nsplit >>= 1;

  unsigned short* Onum = (unsigned short*)d_ws;
  float* Zp = (float*)(Onum + (size_t)nsplit * ONUM_ELEMS);
  unsigned short* Kbb = (unsigned short*)(Zp + (size_t)nsplit * Z_ELEMS);
  unsigned short* Vtb = Kbb + KB_ELEMS;

  const int lLen = NL / nsplit;
  diffattn_prepass<<<dim3(8 * (NL / 64)), dim3(256), 0, stream>>>(K, V, Kbb, Vtb);
  diffattn_partial<<<dim3(8 * 32 * nsplit), dim3(256), 0, stream>>>(
      Q, Kbb, Vtb, Onum, Zp, nsplit, lLen);
  diffattn_combine<<<dim3((ONUM_ELEMS / 8 + 255) / 256), dim3(256), 0, stream>>>(
      Onum, Zp, O, nsplit);
}

// Round 11
// 123.544 us; speedup vs baseline: 1.0431x; 1.0431x over previous
//
#include <hip/hip_runtime.h>
#include <stdint.h>

// DiffAttention: O[n,h,d] = sum_l sigmoid(q_n.k_l) v_l / sum_l sigmoid(q_n.k_l)
// N=L=4096, H=8, M=D=64, fp32 in/out, bf16 MFMA compute.
//
// R11 = R9 core (pi-permuted V, simple sigmoid — R10's paired-rcp chain was
// +4us, reverted; keep bf16 Onum) + CROSS-TILE SOFTWARE PIPELINE:
// iteration t runs QK(t)+sigmoid(t) interleaved with PV(t-1), so matrix /
// trans / LDS pipes overlap WITHIN each wave (R7 proved cross-wave overlap
// never materializes: phase-locked identical blocks serialize pipe use).
// V is triple-buffered (PV(t-1) must survive prefetch(t+1)); K double.
// LDS 40KB x 4 blocks = exactly 160KB/CU. pk in two explicit arrays with
// manual 2x unroll (runtime-indexed register arrays would force scratch).
// Standing lessons: R3 never force 8 waves/EU (spill); R5 no __threadfence
// split-K (L2 storm); R6 residency register-capped ~4 blocks/CU; R8 direct
// global loads thrash L1; 2^22 LDS "conflicts" = b128 phase overhead.

typedef __bf16 bf16x8 __attribute__((ext_vector_type(8)));
typedef __bf16 bf16x2 __attribute__((ext_vector_type(2)));
typedef float  f32x2  __attribute__((ext_vector_type(2)));
typedef float  f32x16 __attribute__((ext_vector_type(16)));
typedef unsigned u32x4 __attribute__((ext_vector_type(4)));

constexpr int NH = 8, MD = 64, NL = 4096, NN = 4096;
constexpr size_t ONUM_ELEMS = (size_t)NN * NH * MD;  // per split (bf16)
constexpr size_t Z_ELEMS    = (size_t)NN * NH;       // per split (f32)
constexpr size_t KB_ELEMS   = (size_t)NH * NL * MD;  // bf16
constexpr size_t VTB_ELEMS  = (size_t)NH * NL * MD;  // bf16

__device__ __forceinline__ unsigned packbf2(float a, float b) {
  bf16x2 t = __builtin_convertvector((f32x2){a, b}, bf16x2);
  return __builtin_bit_cast(unsigned, t);
}

__device__ __forceinline__ void glds16(const void* g, void* l) {
  __builtin_amdgcn_global_load_lds(
      (const __attribute__((address_space(1))) unsigned int*)g,
      (__attribute__((address_space(3))) unsigned int*)l, 16, 0, 0);
}

// ---------------- prepass: one block per (h, l-tile) ----------------
__global__ __launch_bounds__(256) void diffattn_prepass(
    const float* __restrict__ Kg, const float* __restrict__ Vg,
    unsigned short* __restrict__ Kb, unsigned short* __restrict__ Vtb) {
  __shared__ __attribute__((aligned(16))) unsigned short Vt_lds[64 * 64];
  const int tid = threadIdx.x;
  const int h = blockIdx.x & 7;
  const int t = blockIdx.x >> 3;

  // ---- K: [l][h][m] fp32 -> [h][l][m] bf16, 16B chunks swizzled by l&7
#pragma unroll
  for (int e = 0; e < 2; ++e) {
    const int g = tid * 2 + e;
    const int l = g >> 3, c = g & 7;
    const float* kp = Kg + (((size_t)(t * 64 + l) * NH + h) * MD) + c * 8;
    const float4 a = *(const float4*)kp;
    const float4 b = *(const float4*)(kp + 4);
    unsigned out[4] = {packbf2(a.x, a.y), packbf2(a.z, a.w),
                       packbf2(b.x, b.y), packbf2(b.z, b.w)};
    unsigned short* dst =
        Kb + ((size_t)h * NL + t * 64 + l) * MD + ((c ^ (l & 7)) * 8);
    *(uint4*)dst = *(const uint4*)out;
  }

  // ---- V: [l][h][d] fp32 -> LDS transpose (l bit2<->bit3 swapped: makes
  //      PV's A-frag equal QK's D regs) -> [h][t][d][p] bf16, swizzled by d&7
  {
    const int lr = tid & 63, dbase = (tid >> 6) * 16;
    const int pl = (lr & 0x33) | ((lr & 4) << 1) | ((lr & 8) >> 1);
    const float* vp = Vg + (((size_t)(t * 64 + lr) * NH + h) * MD) + dbase;
#pragma unroll
    for (int i = 0; i < 4; ++i) {
      const float4 v = *(const float4*)(vp + i * 4);
      const int d0 = dbase + i * 4;
      Vt_lds[(d0 + 0) * 64 + pl] = __builtin_bit_cast(unsigned short, (__bf16)v.x);
      Vt_lds[(d0 + 1) * 64 + pl] = __builtin_bit_cast(unsigned short, (__bf16)v.y);
      Vt_lds[(d0 + 2) * 64 + pl] = __builtin_bit_cast(unsigned short, (__bf16)v.z);
      Vt_lds[(d0 + 3) * 64 + pl] = __builtin_bit_cast(unsigned short, (__bf16)v.w);
    }
  }
  __syncthreads();
#pragma unroll
  for (int e = 0; e < 2; ++e) {
    const int g = tid * 2 + e;
    const int d = g >> 3, cl = g & 7;
    const uint4 chunk = *(const uint4*)&Vt_lds[d * 64 + cl * 8];
    unsigned short* dst = Vtb + ((size_t)(h * 64 + t) * 64 + d) * 64 +
                          ((cl ^ (d & 7)) * 8);
    *(uint4*)dst = chunk;
  }
}

// ---------------- partial (cross-tile pipelined) ----------------
__global__ __launch_bounds__(256, 4) void diffattn_partial(
    const float* __restrict__ Qg, const unsigned short* __restrict__ Kb,
    const unsigned short* __restrict__ Vtb, unsigned short* __restrict__ Onum,
    float* __restrict__ Zp, int nsplit, int lLen) {
  __shared__ __attribute__((aligned(16))) unsigned short Ksh[2][64 * 64];
  __shared__ __attribute__((aligned(16))) unsigned short Vtsh[3][64 * 64];

  const int tid  = threadIdx.x;
  const int w    = tid >> 6;
  const int lane = tid & 63;
  const int col  = lane & 31;
  const int hi   = lane >> 5;

  const int h     = blockIdx.x & 7;
  const int tmp   = blockIdx.x >> 3;
  const int split = tmp % nsplit;
  const int n0    = (tmp / nsplit) * 128;
  const int lBeg  = split * lLen;

  // Q fragments (B operand), prescaled by -log2e: sigma = rcp(1+exp2(d1)).
  bf16x8 qf[4];
  {
    const float* qp = Qg + ((size_t)(n0 + w * 32 + col) * NH + h) * MD;
    const float c = -1.4426950408889634f;
#pragma unroll
    for (int kc = 0; kc < 4; ++kc) {
      const float4 x = *(const float4*)(qp + kc * 16 + hi * 8);
      const float4 y = *(const float4*)(qp + kc * 16 + hi * 8 + 4);
      bf16x8 f;
      f[0] = (__bf16)(c * x.x); f[1] = (__bf16)(c * x.y);
      f[2] = (__bf16)(c * x.z); f[3] = (__bf16)(c * x.w);
      f[4] = (__bf16)(c * y.x); f[5] = (__bf16)(c * y.y);
      f[6] = (__bf16)(c * y.z); f[7] = (__bf16)(c * y.w);
      qf[kc] = f;
    }
  }

  f32x16 oacc[2];
#pragma unroll
  for (int i = 0; i < 16; ++i) { oacc[0][i] = 0.f; oacc[1][i] = 0.f; }
  float zacc = 0.f;
  const f32x16 zf = {};

  const char* kgh = (const char*)(Kb + (size_t)h * NL * MD);
  const char* vgh = (const char*)(Vtb + (size_t)h * NL * MD);
  const int o = w * 2048 + lane * 16;
  const int T = lLen >> 6;

  auto prefetch = [&](int tile, int kb, int vb) {
    const char* kgb = kgh + (size_t)(lBeg + tile * 64) * 128;
    const char* vgb = vgh + (size_t)(lBeg + tile * 64) * 128;
    glds16(kgb + o,        (char*)Ksh[kb] + w * 2048);
    glds16(kgb + o + 1024, (char*)Ksh[kb] + w * 2048 + 1024);
    glds16(vgb + o,        (char*)Vtsh[vb] + w * 2048);
    glds16(vgb + o + 1024, (char*)Vtsh[vb] + w * 2048 + 1024);
  };
  auto qk_lh = [&](const char* kb, int lh) -> f32x16 {
    const int rowK = lh * 32 + col;
    const char* kp = kb + rowK * 128;
    const int swk = rowK & 7;
    const bf16x8 kf0 = *(const bf16x8*)(kp + ((hi ^ swk) * 16));
    f32x16 d = __builtin_amdgcn_mfma_f32_32x32x16_bf16(kf0, qf[0], zf, 0, 0, 0);
#pragma unroll
    for (int kc = 1; kc < 4; ++kc) {
      const bf16x8 kf = *(const bf16x8*)(kp + (((kc << 1) | hi) ^ swk) * 16);
      d = __builtin_amdgcn_mfma_f32_32x32x16_bf16(kf, qf[kc], d, 0, 0, 0);
    }
    return d;
  };
  auto sig8 = [&](const f32x16& d, unsigned* pkout) {
    float s[16];
#pragma unroll
    for (int r = 0; r < 16; ++r) {
      const float e = __builtin_amdgcn_exp2f(d[r]);
      s[r] = __builtin_amdgcn_rcpf(1.0f + e);
      zacc += s[r];
    }
#pragma unroll
    for (int p = 0; p < 8; ++p) pkout[p] = packbf2(s[2 * p], s[2 * p + 1]);
  };
  auto pv_chunk = [&](const char* vb, int kc2, const unsigned* pk4) {
    const bf16x8 pf = __builtin_bit_cast(bf16x8, *(const u32x4*)pk4);
#pragma unroll
    for (int ds = 0; ds < 2; ++ds) {
      const int rowV = ds * 32 + col;
      const bf16x8 vfr = *(const bf16x8*)(vb + rowV * 128 +
                                          (((kc2 << 1) | hi) ^ (rowV & 7)) * 16);
      oacc[ds] = __builtin_amdgcn_mfma_f32_32x32x16_bf16(pf, vfr, oacc[ds], 0, 0, 0);
    }
  };

  unsigned pkA[16], pkB[16];
  int iPrev = 0, iNext = 2;

  // ---- prologue: tile 0 (no PV yet)
  prefetch(0, 0, 0);
  __syncthreads();            // drains prefetch(0)
  if (T > 1) prefetch(1, 1, 1);
  {
    const char* kb = (const char*)Ksh[0];
    f32x16 da = qk_lh(kb, 0);
    sig8(da, &pkA[0]);
    f32x16 db = qk_lh(kb, 1);
    sig8(db, &pkA[8]);
  }

  // iteration t: barrier; prefetch(t+1); QK(t)+sigmoid(t) interleaved with
  // PV(t-1). pp = pk of tile t-1, pc = pk of tile t.
  auto step = [&](int t, const unsigned* pp, unsigned* pc) {
    __syncthreads();          // drains prefetch(t) (issued one tile ago)
    if (t + 1 < T) prefetch(t + 1, (t + 1) & 1, iNext);
    const char* kb  = (const char*)Ksh[t & 1];
    const char* vbP = (const char*)Vtsh[iPrev];
    f32x16 da = qk_lh(kb, 0);
    pv_chunk(vbP, 0, pp + 0);     // independent of da: fills matrix pipe
    pv_chunk(vbP, 1, pp + 4);
    sig8(da, pc);                 // trans burst overlaps PV MFMAs in flight
    f32x16 db = qk_lh(kb, 1);
    pv_chunk(vbP, 2, pp + 8);
    pv_chunk(vbP, 3, pp + 12);
    sig8(db, pc + 8);
    iPrev = (iPrev == 2) ? 0 : iPrev + 1;
    iNext = (iNext == 2) ? 0 : iNext + 1;
  };

  int t = 1;
  while (t < T) {               // manual 2x unroll keeps pk indices literal
    step(t, pkA, pkB); ++t;
    if (t < T) { step(t, pkB, pkA); ++t; }
  }

  // ---- drain: PV(T-1). After the loop iPrev == (T-1)%3.
  {
    const char* vbP = (const char*)Vtsh[iPrev];
    const unsigned* pp = ((T - 1) & 1) ? pkB : pkA;
    pv_chunk(vbP, 0, pp + 0);
    pv_chunk(vbP, 1, pp + 4);
    pv_chunk(vbP, 2, pp + 8);
    pv_chunk(vbP, 3, pp + 12);
  }

  // ---- epilogue: store bf16 numerator + f32 Z partial
  const float zrow = zacc + __shfl_xor(zacc, 32, 64);
  if (hi == 0)
    Zp[(size_t)split * Z_ELEMS + (size_t)(n0 + w * 32 + col) * NH + h] = zrow;

  unsigned short* onum = Onum + (size_t)split * ONUM_ELEMS;
#pragma unroll
  for (int ds = 0; ds < 2; ++ds) {
    const int d = ds * 32 + col;
#pragma unroll
    for (int r = 0; r < 16; ++r) {
      const int row = (r & 3) + 8 * (r >> 2) + 4 * hi;
      onum[((size_t)(n0 + w * 32 + row) * NH + h) * MD + d] =
          __builtin_bit_cast(unsigned short, (__bf16)oacc[ds][r]);
    }
  }
}

// ---------------- combine: one 8-elem bf16 chunk per thread ----------------
__global__ __launch_bounds__(256) void diffattn_combine(
    const unsigned short* __restrict__ Onum, const float* __restrict__ Zp,
    float* __restrict__ Og, int nsplit) {
  const int idx = blockIdx.x * 256 + threadIdx.x;
  if (idx >= (int)(ONUM_ELEMS / 8)) return;
  const int nh = idx >> 3;          // (n*NH+h)
  const int c8 = (idx & 7) * 8;     // d offset
  float z = 0.f;
  float acc[8] = {0.f, 0.f, 0.f, 0.f, 0.f, 0.f, 0.f, 0.f};
  for (int s = 0; s < nsplit; ++s) {
    z += Zp[(size_t)s * Z_ELEMS + nh];
    const uint4 t = *(const uint4*)(Onum + (size_t)s * ONUM_ELEMS +
                                    (size_t)nh * MD + c8);
    const unsigned u[4] = {t.x, t.y, t.z, t.w};
#pragma unroll
    for (int j = 0; j < 4; ++j) {
      acc[2 * j]     += __builtin_bit_cast(float, u[j] << 16);
      acc[2 * j + 1] += __builtin_bit_cast(float, u[j] & 0xffff0000u);
    }
  }
  const float zi = __builtin_amdgcn_rcpf(z);
  float4 r0 = make_float4(acc[0] * zi, acc[1] * zi, acc[2] * zi, acc[3] * zi);
  float4 r1 = make_float4(acc[4] * zi, acc[5] * zi, acc[6] * zi, acc[7] * zi);
  float* out = Og + (size_t)nh * MD + c8;
  *(float4*)out = r0;
  *(float4*)(out + 4) = r1;
}

extern "C" void kernel_launch(void* const* d_in, const int* in_sizes, int n_in,
                              void* d_out, int out_size, void* d_ws, size_t ws_size,
                              hipStream_t stream) {
  const float* Q = (const float*)d_in[0];
  const float* K = (const float*)d_in[1];
  const float* V = (const float*)d_in[2];
  float* O = (float*)d_out;

  const size_t conv_bytes = (KB_ELEMS + VTB_ELEMS) * sizeof(unsigned short);
  int nsplit = 4;
  while (nsplit > 1 &&
         (size_t)nsplit * (ONUM_ELEMS * 2 + Z_ELEMS * 4) + conv_bytes > ws_size)
    nsplit >>= 1;

  unsigned short* Onum = (unsigned short*)d_ws;
  float* Zp = (float*)(Onum + (size_t)nsplit * ONUM_ELEMS);
  unsigned short* Kbb = (unsigned short*)(Zp + (size_t)nsplit * Z_ELEMS);
  unsigned short* Vtb = Kbb + KB_ELEMS;

  const int lLen = NL / nsplit;
  diffattn_prepass<<<dim3(8 * (NL / 64)), dim3(256), 0, stream>>>(K, V, Kbb, Vtb);
  diffattn_partial<<<dim3(8 * 32 * nsplit), dim3(256), 0, stream>>>(
      Q, Kbb, Vtb, Onum, Zp, nsplit, lLen);
  diffattn_combine<<<dim3((ONUM_ELEMS / 8 + 255) / 256), dim3(256), 0, stream>>>(
      Onum, Zp, O, nsplit);
}